// Round 2
// baseline (127.721 us; speedup 1.0000x reference)
//
#include <hip/hip_runtime.h>

// QuantizedLinear: y[b][o] = scale * sum_k x[b][k]*(qw[o][k]-zp) + bias[o]
// M=16, K=8192, N=8192, all f32. Memory-bound on qw (256 MB read once).
// Floor ~41 us @ 6.3 TB/s.
//
// Structure: K-split x8 for occupancy; within a wave, 16 lane-groups split K
// (kq) and 4 lane-groups split batch (bq), 8 output rows per wave.
// Per 64-k iter: 8 qw loads (256B/instr, 4-way lane broadcast) + 4 x loads
// (1KB/instr) + 128 FMA/lane. Partials combined with unsafeAtomicAdd into
// y pre-initialized with bias (init kernel every launch -> replay-safe).

constexpr int IN_F  = 8192;
constexpr int OUT_F = 8192;
constexpr int BATCH = 16;

constexpr int R      = 8;              // output rows per wave
constexpr int WPB    = 4;              // waves per block (256 threads)
constexpr int KSPLIT = 8;              // K segments (cross-block)
constexpr int SEG    = IN_F / KSPLIT;  // 1024
constexpr int KBLK   = 64;             // k-elements per wave-iteration
constexpr int ITERS  = SEG / KBLK;     // 16

__global__ __launch_bounds__(256)
void init_bias_kernel(const float* __restrict__ bias, float* __restrict__ y) {
    const int i = blockIdx.x * 256 + threadIdx.x;   // 0 .. BATCH*OUT_F-1
    y[i] = bias[i & (OUT_F - 1)];
}

__global__ __launch_bounds__(WPB * 64)
void qlinear_main(const float* __restrict__ x,      // [BATCH][IN_F]
                  const float* __restrict__ qw,     // [OUT_F][IN_F]
                  const float* __restrict__ scale_p,
                  const float* __restrict__ zp_p,
                  float* __restrict__ y)            // [BATCH][OUT_F]
{
    const int lane = threadIdx.x & 63;
    const int wave = threadIdx.x >> 6;
    const int kq = lane & 15;   // K sub-slice within wave
    const int bq = lane >> 4;   // batch quarter (4 batches each)

    constexpr int ROWBLOCKS = OUT_F / (WPB * R);    // 256
    const int seg     = blockIdx.x / ROWBLOCKS;
    const int rowBlk  = blockIdx.x - seg * ROWBLOCKS;
    const int rowBase = (rowBlk * WPB + wave) * R;
    const int kseg    = seg * SEG;

    const float zp    = zp_p[0];
    const float scale = scale_p[0];

    float acc[4][R];   // [local batch j -> b=bq*4+j][row r]
#pragma unroll
    for (int j = 0; j < 4; ++j)
#pragma unroll
        for (int r = 0; r < R; ++r) acc[j][r] = 0.0f;

    for (int it = 0; it < ITERS; ++it) {
        const int k = kseg + it * KBLK + kq * 4;

        // 8 qw loads: 16 lanes (kq=0..15) cover 256B contiguous per row,
        // broadcast across the 4 bq groups.
        float4 w[R];
#pragma unroll
        for (int r = 0; r < R; ++r) {
            const float4 q = *reinterpret_cast<const float4*>(
                qw + (size_t)(rowBase + r) * IN_F + k);
            w[r].x = q.x - zp;
            w[r].y = q.y - zp;
            w[r].z = q.z - zp;
            w[r].w = q.w - zp;
        }

        // 4 x loads: each instr covers 4 batch rows x 256B (distinct lanes).
#pragma unroll
        for (int j = 0; j < 4; ++j) {
            const int b = bq * 4 + j;
            const float4 xv = *reinterpret_cast<const float4*>(x + b * IN_F + k);
#pragma unroll
            for (int r = 0; r < R; ++r) {
                acc[j][r] += xv.x * w[r].x;
                acc[j][r] += xv.y * w[r].y;
                acc[j][r] += xv.z * w[r].z;
                acc[j][r] += xv.w * w[r].w;
            }
        }
    }

    // Reduce over the 16 kq lanes (low 4 bits of lane id).
#pragma unroll
    for (int j = 0; j < 4; ++j)
#pragma unroll
        for (int r = 0; r < R; ++r) {
#pragma unroll
            for (int s = 1; s <= 8; s <<= 1)
                acc[j][r] += __shfl_xor(acc[j][r], s, 64);
        }

    // All lanes hold full kq-sums for their bq. Spread the 128 outputs of
    // this wave across all 64 lanes: lane (bq,kq) writes
    // (b = bq*4 + (kq&3), rows kq>>2 and (kq>>2)+4).
    const int j  = kq & 3;
    const int r0 = kq >> 2;
    const int b  = bq * 4 + j;
    unsafeAtomicAdd(&y[(size_t)b * OUT_F + rowBase + r0],     scale * acc[j][r0]);
    unsafeAtomicAdd(&y[(size_t)b * OUT_F + rowBase + r0 + 4], scale * acc[j][r0 + 4]);
}

extern "C" void kernel_launch(void* const* d_in, const int* in_sizes, int n_in,
                              void* d_out, int out_size, void* d_ws, size_t ws_size,
                              hipStream_t stream) {
    const float* x     = (const float*)d_in[0];
    const float* qw    = (const float*)d_in[1];
    const float* scale = (const float*)d_in[2];
    const float* zp    = (const float*)d_in[3];
    const float* bias  = (const float*)d_in[4];
    float* y = (float*)d_out;

    // 1) y = bias (broadcast) — must run every call (replay-safe).
    init_bias_kernel<<<(BATCH * OUT_F) / 256, 256, 0, stream>>>(bias, y);

    // 2) main: 2048 blocks = 8 K-segments x 256 row-blocks.
    constexpr int ROWBLOCKS = OUT_F / (WPB * R);    // 256
    qlinear_main<<<KSPLIT * ROWBLOCKS, WPB * 64, 0, stream>>>(
        x, qw, scale, zp, y);
}